// Round 11
// baseline (593.367 us; speedup 1.0000x reference)
//
#include <hip/hip_runtime.h>
#include <hip/hip_cooperative_groups.h>

namespace cg = cooperative_groups;

typedef __bf16 bf16x8 __attribute__((ext_vector_type(8)));
typedef __bf16 bf16x4 __attribute__((ext_vector_type(4)));
typedef float  f32x4  __attribute__((ext_vector_type(4)));

#define BN_EPS 1e-5f

// inf-safe mish without clamp: mish(x) = x - 2x / (e^x(e^x+2) + 2)
//   x->+inf: rcp(inf)=0 -> x ; x->-inf: t=0.5 -> 0. 5 VALU + 2 trans.
__device__ __forceinline__ float mish_f(float x) {
    float u = __expf(x);
    float num = u * (u + 2.0f);
    float t = __builtin_amdgcn_rcpf(num + 2.0f);
    return fmaf(-2.0f * x, t, x);
}

// ---------------- fused prep: weights -> B^T bf16  +  dst histogram ----------------
__global__ void prep_hist_kernel(const float* __restrict__ W1, const float* __restrict__ W2,
                                 const float* __restrict__ We, const float* __restrict__ Wr,
                                 __bf16* __restrict__ WcatT, __bf16* __restrict__ W2T,
                                 __bf16* __restrict__ WeeT,
                                 const int* __restrict__ eidx, int* __restrict__ count,
                                 int E_, int wblocks) {
    if ((int)blockIdx.x < wblocks) {
        int i = blockIdx.x * 256 + threadIdx.x;
        if (i < 512 * 128) {
            int n = i >> 7, k = i & 127;
            float v;
            if (n < 128)      v = W1[k * 128 + n];
            else if (n < 256) v = W1[(128 + k) * 128 + (n - 128)];
            else if (n < 384) v = We[(16 + k) * 128 + (n - 256)];
            else              v = Wr[k * 128 + (n - 384)];
            WcatT[(size_t)n * 128 + k] = (__bf16)v;
        } else if (i < 512 * 128 + 128 * 128) {
            int j = i - 512 * 128;
            int n = j >> 7, k = j & 127;
            W2T[n * 128 + k] = (__bf16)W2[k * 128 + n];
        } else if (i < 512 * 128 + 128 * 128 + 128 * 32) {
            int j = i - (512 * 128 + 128 * 128);
            int n = j >> 5, k = j & 31;
            WeeT[n * 32 + k] = (k < 16) ? (__bf16)We[k * 128 + n] : (__bf16)0.0f;
        }
    } else {
        int e = (blockIdx.x - wblocks) * 256 + threadIdx.x;
        if (e < E_) atomicAdd(&count[eidx[E_ + e]], 1);
    }
}

// ---------------- single-block counting-sort scan (replaces scanA+scanB) ----------------
// r11: one dispatch instead of two. 1024 threads, ceil(N/1024) passes with carried
// prefix. 200KB r+w on one CU ~ 8us; removes one graph node from the serial chain.
__global__ __launch_bounds__(1024) void scan_kernel(const int* __restrict__ count,
                                                    int* __restrict__ cursor, int Nn) {
    __shared__ int waveS[16];
    __shared__ int carryS, totS;
    const int t = threadIdx.x;
    const int lane = t & 63;
    const int wv = t >> 6;
    if (t == 0) carryS = 0;
    __syncthreads();
    const int npass = (Nn + 1023) >> 10;
    for (int p = 0; p < npass; ++p) {
        const int idx = (p << 10) + t;
        int v = (idx < Nn) ? count[idx] : 0;
        int x = v;
        #pragma unroll
        for (int s = 1; s < 64; s <<= 1) {
            int y = __shfl(x, (lane >= s) ? (lane - s) : lane);
            if (lane >= s) x += y;
        }
        if (lane == 63) waveS[wv] = x;
        __syncthreads();
        if (t == 0) {
            int run = 0;
            #pragma unroll
            for (int w = 0; w < 16; ++w) { int q = waveS[w]; waveS[w] = run; run += q; }
            totS = run;
        }
        __syncthreads();
        if (idx < Nn) cursor[idx] = carryS + waveS[wv] + (x - v);
        __syncthreads();          // all reads of carryS/waveS done before t0 updates
        if (t == 0) carryS += totS;
        // next pass's waveS write / carryS read are separated from this update by
        // the next pass's own barriers -> no extra barrier needed
    }
}

// ---------------- fused: scatter (sort chain) + precompute (weight chain) ----------------
__global__ __launch_bounds__(256) void scatter_precomp_kernel(
    const int* __restrict__ eidx, int* __restrict__ cursor,
    unsigned int* __restrict__ edgesS, const float* __restrict__ eattr,
    __bf16* __restrict__ eattrP, int E_, int sblocks,
    const float* __restrict__ x, const __bf16* __restrict__ WcatT,
    const float* __restrict__ bias, const float* __restrict__ b1,
    const float* __restrict__ be,
    __bf16* __restrict__ P, float* __restrict__ out, int N_)
{
    if ((int)blockIdx.x < sblocks) {
        int e = blockIdx.x * 256 + threadIdx.x;
        if (e < E_) {
            int d = eidx[E_ + e];
            int s = eidx[e];
            int p = atomicAdd(&cursor[d], 1);
            edgesS[p] = (unsigned)d | ((unsigned)s << 16);
            const float4* ea = reinterpret_cast<const float4*>(eattr + (size_t)e * 16);
            float4 a0 = ea[0], a1 = ea[1], a2 = ea[2], a3 = ea[3];
            bf16x8 o0, o1;
            o0[0] = (__bf16)a0.x; o0[1] = (__bf16)a0.y; o0[2] = (__bf16)a0.z; o0[3] = (__bf16)a0.w;
            o0[4] = (__bf16)a1.x; o0[5] = (__bf16)a1.y; o0[6] = (__bf16)a1.z; o0[7] = (__bf16)a1.w;
            o1[0] = (__bf16)a2.x; o1[1] = (__bf16)a2.y; o1[2] = (__bf16)a2.z; o1[3] = (__bf16)a2.w;
            o1[4] = (__bf16)a3.x; o1[5] = (__bf16)a3.y; o1[6] = (__bf16)a3.z; o1[7] = (__bf16)a3.w;
            __bf16* dp = eattrP + (size_t)p * 16;
            *reinterpret_cast<bf16x8*>(dp)     = o0;
            *reinterpret_cast<bf16x8*>(dp + 8) = o1;
        }
        return;
    }
    const int bb = blockIdx.x - sblocks;
    const int wid  = threadIdx.x >> 6;
    const int lane = threadIdx.x & 63;
    const int quad = lane >> 4;
    const int l16  = lane & 15;

    int rl = bb * 64 + wid * 16 + l16;
    if (rl > N_ - 1) rl = N_ - 1;

    bf16x8 a[4];
    #pragma unroll
    for (int kt = 0; kt < 4; ++kt) {
        const float4* p = reinterpret_cast<const float4*>(x + (size_t)rl * 128 + kt * 32 + quad * 8);
        float4 v0 = p[0], v1 = p[1];
        a[kt][0] = (__bf16)v0.x; a[kt][1] = (__bf16)v0.y; a[kt][2] = (__bf16)v0.z; a[kt][3] = (__bf16)v0.w;
        a[kt][4] = (__bf16)v1.x; a[kt][5] = (__bf16)v1.y; a[kt][6] = (__bf16)v1.z; a[kt][7] = (__bf16)v1.w;
    }

    const f32x4 fz4 = {0.f, 0.f, 0.f, 0.f};
    #pragma unroll
    for (int g = 0; g < 4; ++g) {
        f32x4 acc[8];
        #pragma unroll
        for (int nt = 0; nt < 8; ++nt) acc[nt] = fz4;
        #pragma unroll
        for (int kt = 0; kt < 4; ++kt) {
            #pragma unroll
            for (int nt = 0; nt < 8; ++nt) {
                bf16x8 b = *reinterpret_cast<const bf16x8*>(
                    WcatT + (size_t)((g * 8 + nt) * 16 + l16) * 128 + kt * 32 + quad * 8);
                acc[nt] = __builtin_amdgcn_mfma_f32_16x16x32_bf16(a[kt], b, acc[nt], 0, 0, 0);
            }
        }
        if (g < 3) {
            #pragma unroll
            for (int nt = 0; nt < 8; ++nt) {
                float addv = (g == 2) ? be[nt * 16 + l16] : 0.5f * b1[nt * 16 + l16];
                #pragma unroll
                for (int r = 0; r < 4; ++r) {
                    int row = bb * 64 + wid * 16 + quad * 4 + r;
                    if (row < N_)
                        P[(size_t)row * 384 + g * 128 + nt * 16 + l16] = (__bf16)(acc[nt][r] + addv);
                }
            }
        } else {
            #pragma unroll
            for (int nt = 0; nt < 8; ++nt) {
                float bc = bias[nt * 16 + l16];
                #pragma unroll
                for (int r = 0; r < 4; ++r) {
                    int row = bb * 64 + wid * 16 + quad * 4 + r;
                    if (row < N_)
                        out[(size_t)row * 128 + nt * 16 + l16] = acc[nt][r] + bc;
                }
            }
        }
    }
}

// ---------------- main edge kernel (r6 EXACT — proven 147.2us, do not touch) ----------------
// CLOSED AVENUES (measured): register-cap occupancy (bounds 5/6/8 spill: VGPR 48/40/32,
// FETCH +140..750MB); deeper source ILP (rotation-copy r8 −23us; unroll-3 ping-pong r9
// VGPR stays 64 + 155MB scratch). hipcc pins this kernel at 64 arch VGPR (~128 total/wave
// -> 4 waves/SIMD) and spills rather than materialize deeper pipeline state.
__global__ __launch_bounds__(256, 4) void edge_kernel(
    const __bf16* __restrict__ P,
    const unsigned int* __restrict__ edgesS,
    const __bf16* __restrict__ eattrP,
    const __bf16* __restrict__ W2T, const float* __restrict__ b2,
    const __bf16* __restrict__ WeeT,
    float* __restrict__ aggr, int E_, int nchunks)
{
    __shared__ __align__(16) __bf16 h1s[2][16][128];
    __shared__ __align__(16) float msgS[4][16][36];
    __shared__ int dsts[4][16];

    const int wid  = threadIdx.x >> 6;
    const int lane = threadIdx.x & 63;
    const int quad = lane >> 4;
    const int l16  = lane & 15;
    const int half = lane >> 5;
    const int c32  = lane & 31;

    const int tb0 = 32 * wid;
    const int tb1 = 32 * wid + 16;
    const int chA = 32 * wid + quad * 8;

    // ---- resident A fragments: W2^T (ch x k) and WeeT (ch x k) ----
    bf16x8 aw2[4][2], awe[2];
    #pragma unroll
    for (int kt = 0; kt < 4; ++kt) {
        aw2[kt][0] = *reinterpret_cast<const bf16x8*>(W2T + (tb0 + l16) * 128 + kt * 32 + quad * 8);
        aw2[kt][1] = *reinterpret_cast<const bf16x8*>(W2T + (tb1 + l16) * 128 + kt * 32 + quad * 8);
    }
    awe[0] = *reinterpret_cast<const bf16x8*>(WeeT + (tb0 + l16) * 32 + quad * 8);
    awe[1] = *reinterpret_cast<const bf16x8*>(WeeT + (tb1 + l16) * 32 + quad * 8);

    const f32x4 b2v0 = *reinterpret_cast<const f32x4*>(b2 + tb0 + quad * 4);
    const f32x4 b2v1 = *reinterpret_cast<const f32x4*>(b2 + tb1 + quad * 4);

    const f32x4 fz4 = {0.f, 0.f, 0.f, 0.f};
    int pbuf = 0;

    // ---- contiguous chunk range for this block ----
    const int cpb = (nchunks + gridDim.x - 1) / gridDim.x;
    int ch = blockIdx.x * cpb;
    const int cend = min(ch + cpb, nchunks);
    if (ch >= cend) return;

    // ---- prologue: gather chunk ch + edge word for ch+1 ----
    int em_c = ch * 16 + l16; if (em_c > E_ - 1) em_c = E_ - 1;
    unsigned er_c = edgesS[em_c];
    bf16x8 pav, pbv, ae;
    bf16x4 pe0, pe1;
    {
        unsigned dc = er_c & 0xFFFFu, sc = er_c >> 16;
        pav = *reinterpret_cast<const bf16x8*>(P + dc * 384u + chA);
        pbv = *reinterpret_cast<const bf16x8*>(P + sc * 384u + 128u + chA);
        pe0 = *reinterpret_cast<const bf16x4*>(P + sc * 384u + 256u + tb0 + quad * 4);
        pe1 = *reinterpret_cast<const bf16x4*>(P + sc * 384u + 256u + tb1 + quad * 4);
        if (quad < 2) {
            ae = *reinterpret_cast<const bf16x8*>(eattrP + (unsigned)em_c * 16u + quad * 8);
        } else {
            for (int j = 0; j < 8; ++j) ae[j] = (__bf16)0.0f;
        }
    }
    int em_n; unsigned er_n;
    if (ch + 1 < cend) {
        em_n = (ch + 1) * 16 + l16; if (em_n > E_ - 1) em_n = E_ - 1;
        er_n = edgesS[em_n];
    } else { em_n = em_c; er_n = er_c; }

    // ---- run accumulator carried across chunks ----
    float racc = 0.f; int curd = -1;

    while (true) {
        if (quad == 0) dsts[wid][l16] = (int)(er_c & 0xFFFFu);

        // ---- issue next-chunk gathers (consumed next iteration) ----
        bf16x8 pav_n, pbv_n, ae_n;
        bf16x4 pe0_n, pe1_n;
        {
            unsigned dn = er_n & 0xFFFFu, sn = er_n >> 16;
            pav_n = *reinterpret_cast<const bf16x8*>(P + dn * 384u + chA);
            pbv_n = *reinterpret_cast<const bf16x8*>(P + sn * 384u + 128u + chA);
            pe0_n = *reinterpret_cast<const bf16x4*>(P + sn * 384u + 256u + tb0 + quad * 4);
            pe1_n = *reinterpret_cast<const bf16x4*>(P + sn * 384u + 256u + tb1 + quad * 4);
            if (quad < 2) {
                ae_n = *reinterpret_cast<const bf16x8*>(eattrP + (unsigned)em_n * 16u + quad * 8);
            } else {
                for (int j = 0; j < 8; ++j) ae_n[j] = (__bf16)0.0f;
            }
        }
        // ---- issue edge word for chunk after next ----
        int em_2; unsigned er_2;
        if (ch + 2 < cend) {
            em_2 = (ch + 2) * 16 + l16; if (em_2 > E_ - 1) em_2 = E_ - 1;
            er_2 = edgesS[em_2];
        } else { em_2 = em_n; er_2 = er_n; }

        // ---- h1 = mish(Pa[dst] + Pb[src]) (b1 folded into P), rotated row -> LDS ----
        bf16x8 h1v;
        #pragma unroll
        for (int j = 0; j < 8; ++j)
            h1v[j] = (__bf16)mish_f((float)pav[j] + (float)pbv[j]);
        *reinterpret_cast<bf16x8*>(&h1s[pbuf][l16][(chA + 8 * l16) & 127]) = h1v;

        __syncthreads();   // h1s[pbuf] ready

        // ---- GEMM2 (transposed): D[ch][edge], acc pre-loaded with b2 ----
        f32x4 acc2[2] = {b2v0, b2v1};
        #pragma unroll
        for (int kt = 0; kt < 4; ++kt) {
            bf16x8 bf = *reinterpret_cast<const bf16x8*>(
                &h1s[pbuf][l16][(kt * 32 + quad * 8 + 8 * l16) & 127]);
            acc2[0] = __builtin_amdgcn_mfma_f32_16x16x32_bf16(aw2[kt][0], bf, acc2[0], 0, 0, 0);
            acc2[1] = __builtin_amdgcn_mfma_f32_16x16x32_bf16(aw2[kt][1], bf, acc2[1], 0, 0, 0);
        }

        f32x4 acce[2] = {fz4, fz4};
        acce[0] = __builtin_amdgcn_mfma_f32_16x16x32_bf16(awe[0], ae, acce[0], 0, 0, 0);
        acce[1] = __builtin_amdgcn_mfma_f32_16x16x32_bf16(awe[1], ae, acce[1], 0, 0, 0);

        f32x4 v0, v1;
        #pragma unroll
        for (int r = 0; r < 4; ++r) {
            float he0 = mish_f(acce[0][r] + (float)pe0[r]);
            float he1 = mish_f(acce[1][r] + (float)pe1[r]);
            v0[r] = acc2[0][r] * he0;
            v1[r] = acc2[1][r] * he1;
        }
        if (ch * 16 + 16 > E_) {                  // block-uniform, never taken at E=800000
            if (ch * 16 + l16 >= E_) { v0 = fz4; v1 = fz4; }
        }

        // ---- stage msg to wave-local LDS: [edge l16][ch_local] ----
        *reinterpret_cast<f32x4*>(&msgS[wid][l16][quad * 4])      = v0;
        *reinterpret_cast<f32x4*>(&msgS[wid][l16][16 + quad * 4]) = v1;

        // ---- run-walk reduction: lane = channel; run carried across chunks ----
        #pragma unroll
        for (int i = 0; i < 8; ++i) {
            int row = 8 * half + i;
            float v = msgS[wid][row][c32];
            int d = dsts[wid][row];
            if (d != curd) {
                if (curd >= 0)
                    atomicAdd(aggr + (size_t)curd * 128 + 32 * wid + c32, racc);
                curd = d; racc = v;
            } else racc += v;
        }

        pbuf ^= 1;

        // ---- rotate pipeline ----
        if (++ch >= cend) break;
        em_c = em_n; er_c = er_n; em_n = em_2; er_n = er_2;
        pav = pav_n; pbv = pbv_n; pe0 = pe0_n; pe1 = pe1_n; ae = ae_n;
    }

    // ---- final run flush ----
    if (curd >= 0)
        atomicAdd(aggr + (size_t)curd * 128 + 32 * wid + c32, racc);
}

// ---------------- fused stats + BN (cooperative, replaces stats_kernel + bn_kernel) ----------------
// r11: one cooperative dispatch. Phase 1 = per-channel sum/sumsq atomics; grid.sync();
// Phase 2 = grid-stride normalize. 512 blocks x 256 thr = 2 blocks/CU, co-resident.
__global__ __launch_bounds__(256) void statsbn_kernel(
    float* __restrict__ out, float* __restrict__ stats,
    const float* __restrict__ gamma, const float* __restrict__ beta,
    float invN, int N_)
{
    __shared__ float redS[8][32][8];
    const int c4  = threadIdx.x & 31;
    const int grp = threadIdx.x >> 5;
    float ps[4] = {0.f, 0.f, 0.f, 0.f}, pq[4] = {0.f, 0.f, 0.f, 0.f};

    for (int n = blockIdx.x * 8 + grp; n < N_; n += gridDim.x * 8) {
        float4 v = reinterpret_cast<const float4*>(out)[(size_t)n * 32 + c4];
        ps[0] += v.x; ps[1] += v.y; ps[2] += v.z; ps[3] += v.w;
        pq[0] += v.x * v.x; pq[1] += v.y * v.y; pq[2] += v.z * v.z; pq[3] += v.w * v.w;
    }
    #pragma unroll
    for (int j = 0; j < 4; ++j) { redS[grp][c4][j] = ps[j]; redS[grp][c4][4 + j] = pq[j]; }
    __syncthreads();
    {
        const int cc = threadIdx.x & 31, jj = threadIdx.x >> 5;
        float s = 0.f;
        #pragma unroll
        for (int k = 0; k < 8; ++k) s += redS[k][cc][jj];
        if (jj < 4) atomicAdd(&stats[cc * 4 + jj], s);
        else        atomicAdd(&stats[128 + cc * 4 + (jj - 4)], s);
    }

    __threadfence();
    cg::this_grid().sync();

    // ---- phase 2: BN normalize, grid-stride over float4s ----
    const int total4 = N_ * 32;
    for (int i = blockIdx.x * 256 + threadIdx.x; i < total4; i += gridDim.x * 256) {
        int c0 = (i & 31) * 4;
        float4 v = reinterpret_cast<float4*>(out)[i];
        float o[4] = {v.x, v.y, v.z, v.w};
        #pragma unroll
        for (int j = 0; j < 4; ++j) {
            int c = c0 + j;
            float mean  = stats[c] * invN;
            float var   = stats[128 + c] * invN - mean * mean;
            float scale = gamma[c] * rsqrtf(var + BN_EPS);
            o[j] = (o[j] - mean) * scale + beta[c];
        }
        v.x = o[0]; v.y = o[1]; v.z = o[2]; v.w = o[3];
        reinterpret_cast<float4*>(out)[i] = v;
    }
}

extern "C" void kernel_launch(void* const* d_in, const int* in_sizes, int n_in,
                              void* d_out, int out_size, void* d_ws, size_t ws_size,
                              hipStream_t stream)
{
    const float* x     = (const float*)d_in[0];
    const int*   eidx  = (const int*)d_in[1];
    const float* eattr = (const float*)d_in[2];
    const float* W1    = (const float*)d_in[3];
    const float* b1    = (const float*)d_in[4];
    const float* W2    = (const float*)d_in[5];
    const float* b2    = (const float*)d_in[6];
    const float* We    = (const float*)d_in[7];
    const float* be    = (const float*)d_in[8];
    const float* Wroot = (const float*)d_in[9];
    const float* bias  = (const float*)d_in[10];
    const float* gamma = (const float*)d_in[11];
    const float* beta  = (const float*)d_in[12];

    const int N_ = in_sizes[0] / 128;
    const int E_ = in_sizes[1] / 2;

    char* ws = (char*)d_ws;
    size_t off = 0;
    __bf16* P     = (__bf16*)(ws + off); off += (size_t)N_ * 384 * 2;
    __bf16* WcatT = (__bf16*)(ws + off); off += 512 * 128 * 2;
    __bf16* W2T   = (__bf16*)(ws + off); off += 128 * 128 * 2;
    __bf16* WeeT  = (__bf16*)(ws + off); off += 128 * 32 * 2;
    off = (off + 15) & ~(size_t)15;
    float* stats  = (float*)(ws + off);  off += 256 * 4;       // stats+count: one memset
    int* count    = (int*)(ws + off);    off += (size_t)N_ * 4;
    size_t zero_bytes = 256 * 4 + (size_t)N_ * 4;
    int* cursor   = (int*)(ws + off);    off += (size_t)N_ * 4;
    off = (off + 15) & ~(size_t)15;
    unsigned int* edgesS = (unsigned int*)(ws + off); off += (size_t)E_ * 4;
    off = (off + 15) & ~(size_t)15;
    __bf16* eattrP = (__bf16*)(ws + off); off += (size_t)E_ * 16 * 2;

    float* out = (float*)d_out;

    hipMemsetAsync(stats, 0, zero_bytes, stream);

    int wtot = 512 * 128 + 128 * 128 + 128 * 32;
    int wblocks = (wtot + 255) / 256;
    int eblocks = (E_ + 255) / 256;
    prep_hist_kernel<<<wblocks + eblocks, 256, 0, stream>>>(W1, W2, We, Wroot,
                                                            WcatT, W2T, WeeT,
                                                            eidx, count, E_, wblocks);

    scan_kernel<<<1, 1024, 0, stream>>>(count, cursor, N_);

    int pblocks = (N_ + 63) / 64;
    scatter_precomp_kernel<<<eblocks + pblocks, 256, 0, stream>>>(
        eidx, cursor, edgesS, eattr, eattrP, E_, eblocks,
        x, WcatT, bias, b1, be, P, out, N_);

    int nchunks = (E_ + 15) / 16;
    edge_kernel<<<2048, 256, 0, stream>>>(P, edgesS, eattrP,
                                          W2T, b2, WeeT, out, E_, nchunks);

    {
        float invN = 1.0f / (float)N_;
        void* cargs[] = { (void*)&out, (void*)&stats, (void*)&gamma, (void*)&beta,
                          (void*)&invN, (void*)&N_ };
        hipLaunchCooperativeKernel((void*)statsbn_kernel, dim3(512), dim3(256),
                                   cargs, 0, stream);
    }
}

// Round 12
// 441.517 us; speedup vs baseline: 1.3439x; 1.3439x over previous
//
#include <hip/hip_runtime.h>

typedef __bf16 bf16x8 __attribute__((ext_vector_type(8)));
typedef __bf16 bf16x4 __attribute__((ext_vector_type(4)));
typedef float  f32x4  __attribute__((ext_vector_type(4)));

#define BN_EPS 1e-5f

// inf-safe mish without clamp: mish(x) = x - 2x / (e^x(e^x+2) + 2)
//   x->+inf: rcp(inf)=0 -> x ; x->-inf: t=0.5 -> 0. 5 VALU + 2 trans.
__device__ __forceinline__ float mish_f(float x) {
    float u = __expf(x);
    float num = u * (u + 2.0f);
    float t = __builtin_amdgcn_rcpf(num + 2.0f);
    return fmaf(-2.0f * x, t, x);
}

// ---------------- fused prep: weights -> B^T bf16  +  dst histogram ----------------
__global__ void prep_hist_kernel(const float* __restrict__ W1, const float* __restrict__ W2,
                                 const float* __restrict__ We, const float* __restrict__ Wr,
                                 __bf16* __restrict__ WcatT, __bf16* __restrict__ W2T,
                                 __bf16* __restrict__ WeeT,
                                 const int* __restrict__ eidx, int* __restrict__ count,
                                 int E_, int wblocks) {
    if ((int)blockIdx.x < wblocks) {
        int i = blockIdx.x * 256 + threadIdx.x;
        if (i < 512 * 128) {
            int n = i >> 7, k = i & 127;
            float v;
            if (n < 128)      v = W1[k * 128 + n];
            else if (n < 256) v = W1[(128 + k) * 128 + (n - 128)];
            else if (n < 384) v = We[(16 + k) * 128 + (n - 256)];
            else              v = Wr[k * 128 + (n - 384)];
            WcatT[(size_t)n * 128 + k] = (__bf16)v;
        } else if (i < 512 * 128 + 128 * 128) {
            int j = i - 512 * 128;
            int n = j >> 7, k = j & 127;
            W2T[n * 128 + k] = (__bf16)W2[k * 128 + n];
        } else if (i < 512 * 128 + 128 * 128 + 128 * 32) {
            int j = i - (512 * 128 + 128 * 128);
            int n = j >> 5, k = j & 31;
            WeeT[n * 32 + k] = (k < 16) ? (__bf16)We[k * 128 + n] : (__bf16)0.0f;
        }
    } else {
        int e = (blockIdx.x - wblocks) * 256 + threadIdx.x;
        if (e < E_) atomicAdd(&count[eidx[E_ + e]], 1);
    }
}

// ---------------- counting sort scan (parallel) ----------------
// r11 lesson: do NOT fuse into a single-block scan (49 serial latency-bound passes
// ≈ +100us). This two-kernel parallel form is proven fast.
__global__ __launch_bounds__(1024) void scanA_kernel(const int* __restrict__ count,
                                                     int* __restrict__ cursor,
                                                     int* __restrict__ bsums, int Nn) {
    __shared__ int waveS[16];
    const int t = threadIdx.x;
    const int lane = t & 63;
    const int wv = t >> 6;
    const int i0 = blockIdx.x * 4096 + t * 4;
    int c0 = 0, c1 = 0, c2 = 0, c3 = 0;
    if (i0 + 3 < Nn) {
        int4 c = *reinterpret_cast<const int4*>(count + i0);
        c0 = c.x; c1 = c.y; c2 = c.z; c3 = c.w;
    } else if (i0 < Nn) {
        c0 = count[i0];
        if (i0 + 1 < Nn) c1 = count[i0 + 1];
        if (i0 + 2 < Nn) c2 = count[i0 + 2];
    }
    int s1 = c0 + c1, s2 = s1 + c2, tot = s2 + c3;
    int x = tot;
    #pragma unroll
    for (int s = 1; s < 64; s <<= 1) {
        int y = __shfl(x, (lane >= s) ? (lane - s) : lane);
        if (lane >= s) x += y;
    }
    if (lane == 63) waveS[wv] = x;
    __syncthreads();
    if (t == 0) {
        int run = 0;
        #pragma unroll
        for (int w = 0; w < 16; ++w) { int v = waveS[w]; waveS[w] = run; run += v; }
        bsums[blockIdx.x] = run;
    }
    __syncthreads();
    int excl = waveS[wv] + (x - tot);
    if (i0 + 3 < Nn) {
        int4 o; o.x = excl; o.y = excl + c0; o.z = excl + s1; o.w = excl + s2;
        *reinterpret_cast<int4*>(cursor + i0) = o;
    } else if (i0 < Nn) {
        cursor[i0] = excl;
        if (i0 + 1 < Nn) cursor[i0 + 1] = excl + c0;
        if (i0 + 2 < Nn) cursor[i0 + 2] = excl + s1;
    }
}

__global__ __launch_bounds__(1024) void scanB_kernel(int* __restrict__ cursor,
                                                     const int* __restrict__ bsums, int Nn) {
    __shared__ int offS;
    const int b = blockIdx.x;
    if (threadIdx.x == 0) {
        int s = 0;
        for (int i = 0; i < b; ++i) s += bsums[i];
        offS = s;
    }
    __syncthreads();
    const int o = offS;
    if (b == 0) return;
    const int i0 = b * 4096 + threadIdx.x * 4;
    if (i0 + 3 < Nn) {
        int4 v = *reinterpret_cast<int4*>(cursor + i0);
        v.x += o; v.y += o; v.z += o; v.w += o;
        *reinterpret_cast<int4*>(cursor + i0) = v;
    } else {
        #pragma unroll
        for (int j = 0; j < 4; ++j) if (i0 + j < Nn) cursor[i0 + j] += o;
    }
}

// ---------------- fused: scatter (sort chain) + precompute (weight chain) ----------------
__global__ __launch_bounds__(256) void scatter_precomp_kernel(
    const int* __restrict__ eidx, int* __restrict__ cursor,
    unsigned int* __restrict__ edgesS, const float* __restrict__ eattr,
    __bf16* __restrict__ eattrP, int E_, int sblocks,
    const float* __restrict__ x, const __bf16* __restrict__ WcatT,
    const float* __restrict__ bias, const float* __restrict__ b1,
    const float* __restrict__ be,
    __bf16* __restrict__ P, float* __restrict__ out, int N_)
{
    if ((int)blockIdx.x < sblocks) {
        int e = blockIdx.x * 256 + threadIdx.x;
        if (e < E_) {
            int d = eidx[E_ + e];
            int s = eidx[e];
            int p = atomicAdd(&cursor[d], 1);
            edgesS[p] = (unsigned)d | ((unsigned)s << 16);
            const float4* ea = reinterpret_cast<const float4*>(eattr + (size_t)e * 16);
            float4 a0 = ea[0], a1 = ea[1], a2 = ea[2], a3 = ea[3];
            bf16x8 o0, o1;
            o0[0] = (__bf16)a0.x; o0[1] = (__bf16)a0.y; o0[2] = (__bf16)a0.z; o0[3] = (__bf16)a0.w;
            o0[4] = (__bf16)a1.x; o0[5] = (__bf16)a1.y; o0[6] = (__bf16)a1.z; o0[7] = (__bf16)a1.w;
            o1[0] = (__bf16)a2.x; o1[1] = (__bf16)a2.y; o1[2] = (__bf16)a2.z; o1[3] = (__bf16)a2.w;
            o1[4] = (__bf16)a3.x; o1[5] = (__bf16)a3.y; o1[6] = (__bf16)a3.z; o1[7] = (__bf16)a3.w;
            __bf16* dp = eattrP + (size_t)p * 16;
            *reinterpret_cast<bf16x8*>(dp)     = o0;
            *reinterpret_cast<bf16x8*>(dp + 8) = o1;
        }
        return;
    }
    const int bb = blockIdx.x - sblocks;
    const int wid  = threadIdx.x >> 6;
    const int lane = threadIdx.x & 63;
    const int quad = lane >> 4;
    const int l16  = lane & 15;

    int rl = bb * 64 + wid * 16 + l16;
    if (rl > N_ - 1) rl = N_ - 1;

    bf16x8 a[4];
    #pragma unroll
    for (int kt = 0; kt < 4; ++kt) {
        const float4* p = reinterpret_cast<const float4*>(x + (size_t)rl * 128 + kt * 32 + quad * 8);
        float4 v0 = p[0], v1 = p[1];
        a[kt][0] = (__bf16)v0.x; a[kt][1] = (__bf16)v0.y; a[kt][2] = (__bf16)v0.z; a[kt][3] = (__bf16)v0.w;
        a[kt][4] = (__bf16)v1.x; a[kt][5] = (__bf16)v1.y; a[kt][6] = (__bf16)v1.z; a[kt][7] = (__bf16)v1.w;
    }

    const f32x4 fz4 = {0.f, 0.f, 0.f, 0.f};
    #pragma unroll
    for (int g = 0; g < 4; ++g) {
        f32x4 acc[8];
        #pragma unroll
        for (int nt = 0; nt < 8; ++nt) acc[nt] = fz4;
        #pragma unroll
        for (int kt = 0; kt < 4; ++kt) {
            #pragma unroll
            for (int nt = 0; nt < 8; ++nt) {
                bf16x8 b = *reinterpret_cast<const bf16x8*>(
                    WcatT + (size_t)((g * 8 + nt) * 16 + l16) * 128 + kt * 32 + quad * 8);
                acc[nt] = __builtin_amdgcn_mfma_f32_16x16x32_bf16(a[kt], b, acc[nt], 0, 0, 0);
            }
        }
        if (g < 3) {
            #pragma unroll
            for (int nt = 0; nt < 8; ++nt) {
                float addv = (g == 2) ? be[nt * 16 + l16] : 0.5f * b1[nt * 16 + l16];
                #pragma unroll
                for (int r = 0; r < 4; ++r) {
                    int row = bb * 64 + wid * 16 + quad * 4 + r;
                    if (row < N_)
                        P[(size_t)row * 384 + g * 128 + nt * 16 + l16] = (__bf16)(acc[nt][r] + addv);
                }
            }
        } else {
            #pragma unroll
            for (int nt = 0; nt < 8; ++nt) {
                float bc = bias[nt * 16 + l16];
                #pragma unroll
                for (int r = 0; r < 4; ++r) {
                    int row = bb * 64 + wid * 16 + quad * 4 + r;
                    if (row < N_)
                        out[(size_t)row * 128 + nt * 16 + l16] = acc[nt][r] + bc;
                }
            }
        }
    }
}

// ---------------- main edge kernel (proven best: 146.9us) ----------------
// CLOSED AVENUES (measured): register-cap occupancy (bounds 5/6/8 spill: VGPR 48/40/32,
// FETCH +140..750MB); deeper source ILP (rotation-copy r8 −23us; unroll-3 ping-pong r9
// VGPR stays 64 + 155MB scratch); dispatch fusion (r11: single-block scan +100us,
// cooperative statsbn overhead — total 593us). hipcc pins this kernel at 64 arch VGPR
// (~128 total/wave -> 4 waves/SIMD) and spills rather than materialize deeper state.
// Structure: depth-1 software pipeline (r5: 219->148), contiguous chunk ranges +
// carried run accumulator (r6: WRITE 84->53MB), b1/be folded into P, b2 in acc init,
// sorted bf16 eattrP stream, 4B edge records.
__global__ __launch_bounds__(256, 4) void edge_kernel(
    const __bf16* __restrict__ P,
    const unsigned int* __restrict__ edgesS,
    const __bf16* __restrict__ eattrP,
    const __bf16* __restrict__ W2T, const float* __restrict__ b2,
    const __bf16* __restrict__ WeeT,
    float* __restrict__ aggr, int E_, int nchunks)
{
    __shared__ __align__(16) __bf16 h1s[2][16][128];
    __shared__ __align__(16) float msgS[4][16][36];
    __shared__ int dsts[4][16];

    const int wid  = threadIdx.x >> 6;
    const int lane = threadIdx.x & 63;
    const int quad = lane >> 4;
    const int l16  = lane & 15;
    const int half = lane >> 5;
    const int c32  = lane & 31;

    const int tb0 = 32 * wid;
    const int tb1 = 32 * wid + 16;
    const int chA = 32 * wid + quad * 8;

    // ---- resident A fragments: W2^T (ch x k) and WeeT (ch x k) ----
    bf16x8 aw2[4][2], awe[2];
    #pragma unroll
    for (int kt = 0; kt < 4; ++kt) {
        aw2[kt][0] = *reinterpret_cast<const bf16x8*>(W2T + (tb0 + l16) * 128 + kt * 32 + quad * 8);
        aw2[kt][1] = *reinterpret_cast<const bf16x8*>(W2T + (tb1 + l16) * 128 + kt * 32 + quad * 8);
    }
    awe[0] = *reinterpret_cast<const bf16x8*>(WeeT + (tb0 + l16) * 32 + quad * 8);
    awe[1] = *reinterpret_cast<const bf16x8*>(WeeT + (tb1 + l16) * 32 + quad * 8);

    const f32x4 b2v0 = *reinterpret_cast<const f32x4*>(b2 + tb0 + quad * 4);
    const f32x4 b2v1 = *reinterpret_cast<const f32x4*>(b2 + tb1 + quad * 4);

    const f32x4 fz4 = {0.f, 0.f, 0.f, 0.f};
    int pbuf = 0;

    // ---- contiguous chunk range for this block ----
    const int cpb = (nchunks + gridDim.x - 1) / gridDim.x;
    int ch = blockIdx.x * cpb;
    const int cend = min(ch + cpb, nchunks);
    if (ch >= cend) return;

    // ---- prologue: gather chunk ch + edge word for ch+1 ----
    int em_c = ch * 16 + l16; if (em_c > E_ - 1) em_c = E_ - 1;
    unsigned er_c = edgesS[em_c];
    bf16x8 pav, pbv, ae;
    bf16x4 pe0, pe1;
    {
        unsigned dc = er_c & 0xFFFFu, sc = er_c >> 16;
        pav = *reinterpret_cast<const bf16x8*>(P + dc * 384u + chA);
        pbv = *reinterpret_cast<const bf16x8*>(P + sc * 384u + 128u + chA);
        pe0 = *reinterpret_cast<const bf16x4*>(P + sc * 384u + 256u + tb0 + quad * 4);
        pe1 = *reinterpret_cast<const bf16x4*>(P + sc * 384u + 256u + tb1 + quad * 4);
        if (quad < 2) {
            ae = *reinterpret_cast<const bf16x8*>(eattrP + (unsigned)em_c * 16u + quad * 8);
        } else {
            for (int j = 0; j < 8; ++j) ae[j] = (__bf16)0.0f;
        }
    }
    int em_n; unsigned er_n;
    if (ch + 1 < cend) {
        em_n = (ch + 1) * 16 + l16; if (em_n > E_ - 1) em_n = E_ - 1;
        er_n = edgesS[em_n];
    } else { em_n = em_c; er_n = er_c; }

    // ---- run accumulator carried across chunks ----
    float racc = 0.f; int curd = -1;

    while (true) {
        if (quad == 0) dsts[wid][l16] = (int)(er_c & 0xFFFFu);

        // ---- issue next-chunk gathers (consumed next iteration) ----
        bf16x8 pav_n, pbv_n, ae_n;
        bf16x4 pe0_n, pe1_n;
        {
            unsigned dn = er_n & 0xFFFFu, sn = er_n >> 16;
            pav_n = *reinterpret_cast<const bf16x8*>(P + dn * 384u + chA);
            pbv_n = *reinterpret_cast<const bf16x8*>(P + sn * 384u + 128u + chA);
            pe0_n = *reinterpret_cast<const bf16x4*>(P + sn * 384u + 256u + tb0 + quad * 4);
            pe1_n = *reinterpret_cast<const bf16x4*>(P + sn * 384u + 256u + tb1 + quad * 4);
            if (quad < 2) {
                ae_n = *reinterpret_cast<const bf16x8*>(eattrP + (unsigned)em_n * 16u + quad * 8);
            } else {
                for (int j = 0; j < 8; ++j) ae_n[j] = (__bf16)0.0f;
            }
        }
        // ---- issue edge word for chunk after next ----
        int em_2; unsigned er_2;
        if (ch + 2 < cend) {
            em_2 = (ch + 2) * 16 + l16; if (em_2 > E_ - 1) em_2 = E_ - 1;
            er_2 = edgesS[em_2];
        } else { em_2 = em_n; er_2 = er_n; }

        // ---- h1 = mish(Pa[dst] + Pb[src]) (b1 folded into P), rotated row -> LDS ----
        bf16x8 h1v;
        #pragma unroll
        for (int j = 0; j < 8; ++j)
            h1v[j] = (__bf16)mish_f((float)pav[j] + (float)pbv[j]);
        *reinterpret_cast<bf16x8*>(&h1s[pbuf][l16][(chA + 8 * l16) & 127]) = h1v;

        __syncthreads();   // h1s[pbuf] ready

        // ---- GEMM2 (transposed): D[ch][edge], acc pre-loaded with b2 ----
        f32x4 acc2[2] = {b2v0, b2v1};
        #pragma unroll
        for (int kt = 0; kt < 4; ++kt) {
            bf16x8 bf = *reinterpret_cast<const bf16x8*>(
                &h1s[pbuf][l16][(kt * 32 + quad * 8 + 8 * l16) & 127]);
            acc2[0] = __builtin_amdgcn_mfma_f32_16x16x32_bf16(aw2[kt][0], bf, acc2[0], 0, 0, 0);
            acc2[1] = __builtin_amdgcn_mfma_f32_16x16x32_bf16(aw2[kt][1], bf, acc2[1], 0, 0, 0);
        }

        f32x4 acce[2] = {fz4, fz4};
        acce[0] = __builtin_amdgcn_mfma_f32_16x16x32_bf16(awe[0], ae, acce[0], 0, 0, 0);
        acce[1] = __builtin_amdgcn_mfma_f32_16x16x32_bf16(awe[1], ae, acce[1], 0, 0, 0);

        f32x4 v0, v1;
        #pragma unroll
        for (int r = 0; r < 4; ++r) {
            float he0 = mish_f(acce[0][r] + (float)pe0[r]);
            float he1 = mish_f(acce[1][r] + (float)pe1[r]);
            v0[r] = acc2[0][r] * he0;
            v1[r] = acc2[1][r] * he1;
        }
        if (ch * 16 + 16 > E_) {                  // block-uniform, never taken at E=800000
            if (ch * 16 + l16 >= E_) { v0 = fz4; v1 = fz4; }
        }

        // ---- stage msg to wave-local LDS: [edge l16][ch_local] ----
        *reinterpret_cast<f32x4*>(&msgS[wid][l16][quad * 4])      = v0;
        *reinterpret_cast<f32x4*>(&msgS[wid][l16][16 + quad * 4]) = v1;

        // ---- run-walk reduction: lane = channel; run carried across chunks ----
        #pragma unroll
        for (int i = 0; i < 8; ++i) {
            int row = 8 * half + i;
            float v = msgS[wid][row][c32];
            int d = dsts[wid][row];
            if (d != curd) {
                if (curd >= 0)
                    atomicAdd(aggr + (size_t)curd * 128 + 32 * wid + c32, racc);
                curd = d; racc = v;
            } else racc += v;
        }

        pbuf ^= 1;

        // ---- rotate pipeline ----
        if (++ch >= cend) break;
        em_c = em_n; er_c = er_n; em_n = em_2; er_n = er_2;
        pav = pav_n; pbv = pbv_n; pe0 = pe0_n; pe1 = pe1_n; ae = ae_n;
    }

    // ---- final run flush ----
    if (curd >= 0)
        atomicAdd(aggr + (size_t)curd * 128 + 32 * wid + c32, racc);
}

// ---------------- stats: per-channel sum & sumsq of out ----------------
__global__ __launch_bounds__(256) void stats_kernel(
    const float* __restrict__ out, float* __restrict__ stats, int N_)
{
    __shared__ float redS[8][32][8];
    const int c4  = threadIdx.x & 31;
    const int grp = threadIdx.x >> 5;
    float ps[4] = {0.f, 0.f, 0.f, 0.f}, pq[4] = {0.f, 0.f, 0.f, 0.f};

    for (int n = blockIdx.x * 8 + grp; n < N_; n += gridDim.x * 8) {
        float4 v = reinterpret_cast<const float4*>(out)[(size_t)n * 32 + c4];
        ps[0] += v.x; ps[1] += v.y; ps[2] += v.z; ps[3] += v.w;
        pq[0] += v.x * v.x; pq[1] += v.y * v.y; pq[2] += v.z * v.z; pq[3] += v.w * v.w;
    }
    #pragma unroll
    for (int j = 0; j < 4; ++j) { redS[grp][c4][j] = ps[j]; redS[grp][c4][4 + j] = pq[j]; }
    __syncthreads();
    {
        const int cc = threadIdx.x & 31, jj = threadIdx.x >> 5;
        float s = 0.f;
        #pragma unroll
        for (int k = 0; k < 8; ++k) s += redS[k][cc][jj];
        if (jj < 4) atomicAdd(&stats[cc * 4 + jj], s);
        else        atomicAdd(&stats[128 + cc * 4 + (jj - 4)], s);
    }
}

// ---------------- BN finalize ----------------
__global__ void bn_kernel(float* __restrict__ out, const float* __restrict__ stats,
                          const float* __restrict__ gamma, const float* __restrict__ beta,
                          float invN, int total4)
{
    int i = blockIdx.x * blockDim.x + threadIdx.x;
    if (i >= total4) return;
    int c0 = (i & 31) * 4;
    float4 v = reinterpret_cast<float4*>(out)[i];
    float o[4] = {v.x, v.y, v.z, v.w};
    #pragma unroll
    for (int j = 0; j < 4; ++j) {
        int c = c0 + j;
        float mean  = stats[c] * invN;
        float var   = stats[128 + c] * invN - mean * mean;
        float scale = gamma[c] * rsqrtf(var + BN_EPS);
        o[j] = (o[j] - mean) * scale + beta[c];
    }
    v.x = o[0]; v.y = o[1]; v.z = o[2]; v.w = o[3];
    reinterpret_cast<float4*>(out)[i] = v;
}

extern "C" void kernel_launch(void* const* d_in, const int* in_sizes, int n_in,
                              void* d_out, int out_size, void* d_ws, size_t ws_size,
                              hipStream_t stream)
{
    const float* x     = (const float*)d_in[0];
    const int*   eidx  = (const int*)d_in[1];
    const float* eattr = (const float*)d_in[2];
    const float* W1    = (const float*)d_in[3];
    const float* b1    = (const float*)d_in[4];
    const float* W2    = (const float*)d_in[5];
    const float* b2    = (const float*)d_in[6];
    const float* We    = (const float*)d_in[7];
    const float* be    = (const float*)d_in[8];
    const float* Wroot = (const float*)d_in[9];
    const float* bias  = (const float*)d_in[10];
    const float* gamma = (const float*)d_in[11];
    const float* beta  = (const float*)d_in[12];

    const int N_ = in_sizes[0] / 128;
    const int E_ = in_sizes[1] / 2;

    char* ws = (char*)d_ws;
    size_t off = 0;
    __bf16* P     = (__bf16*)(ws + off); off += (size_t)N_ * 384 * 2;
    __bf16* WcatT = (__bf16*)(ws + off); off += 512 * 128 * 2;
    __bf16* W2T   = (__bf16*)(ws + off); off += 128 * 128 * 2;
    __bf16* WeeT  = (__bf16*)(ws + off); off += 128 * 32 * 2;
    off = (off + 15) & ~(size_t)15;
    float* stats  = (float*)(ws + off);  off += 256 * 4;       // stats+count: one memset
    int* count    = (int*)(ws + off);    off += (size_t)N_ * 4;
    size_t zero_bytes = 256 * 4 + (size_t)N_ * 4;
    int* cursor   = (int*)(ws + off);    off += (size_t)N_ * 4;
    int* bsums    = (int*)(ws + off);    off += 64 * 4;
    off = (off + 15) & ~(size_t)15;
    unsigned int* edgesS = (unsigned int*)(ws + off); off += (size_t)E_ * 4;
    off = (off + 15) & ~(size_t)15;
    __bf16* eattrP = (__bf16*)(ws + off); off += (size_t)E_ * 16 * 2;

    float* out = (float*)d_out;

    hipMemsetAsync(stats, 0, zero_bytes, stream);

    int wtot = 512 * 128 + 128 * 128 + 128 * 32;
    int wblocks = (wtot + 255) / 256;
    int eblocks = (E_ + 255) / 256;
    prep_hist_kernel<<<wblocks + eblocks, 256, 0, stream>>>(W1, W2, We, Wroot,
                                                            WcatT, W2T, WeeT,
                                                            eidx, count, E_, wblocks);

    int nb = (N_ + 4095) / 4096;
    scanA_kernel<<<nb, 1024, 0, stream>>>(count, cursor, bsums, N_);
    scanB_kernel<<<nb, 1024, 0, stream>>>(cursor, bsums, N_);

    int pblocks = (N_ + 63) / 64;
    scatter_precomp_kernel<<<eblocks + pblocks, 256, 0, stream>>>(
        eidx, cursor, edgesS, eattr, eattrP, E_, eblocks,
        x, WcatT, bias, b1, be, P, out, N_);

    int nchunks = (E_ + 15) / 16;
    edge_kernel<<<2048, 256, 0, stream>>>(P, edgesS, eattrP,
                                          W2T, b2, WeeT, out, E_, nchunks);

    stats_kernel<<<512, 256, 0, stream>>>(out, stats, N_);

    bn_kernel<<<(N_ * 32 + 255) / 256, 256, 0, stream>>>(out, stats, gamma, beta,
                                                         1.0f / (float)N_, N_ * 32);
}